// Round 1
// baseline (43.070 us; speedup 1.0000x reference)
//
#include <hip/hip_runtime.h>

// GD_lagrange_multi fused kernel for MI355X (gfx950).
// Shapes fixed by setup_inputs(): W=4, B=32, S=16, G=1024, niter=20.
// One block per (w,b): 512 threads = 8 waves, wave owns 128 g-rows = 8 MFMA tiles.
//
// Unified lane layout (per 16x16 tile), lane l = 16*q + m (q=(l>>4)&3, m=l&15):
//   Omega master (f32): Om[t][r] = Omega[g = g0+16t+4q+r][j = m]
//   A-frag of Omega^T / B-frag of Yp^T / B-frag of lam: elem e <-> (k = 4q+e, col/row = m)
//   C/D: reg r <-> (row = 4q+r, col = m)
// These coincide for K=16 MFMAs, so no cross-lane data movement except:
//   - row norms: DPP row_ror reduction over the 16-lane row (j axis)
//   - grad_lam^T -> lam orientation: transposed via the LDS cross-wave reduce buffer

typedef float    f32x4 __attribute__((ext_vector_type(4)));
typedef _Float16 f16x4 __attribute__((ext_vector_type(4)));

#define MUv 1e-3f
#define ROv 1e-3f

// add value rotated within the 16-lane DPP row; 4 stages => all lanes hold row total
#define ROR_ADD(s, CTRL)                                                      \
  s += __int_as_float(__builtin_amdgcn_update_dpp(                            \
      0, __float_as_int(s), (CTRL), 0xF, 0xF, true))

__device__ __forceinline__ float rowsum16(float x) {
  float s = x;
  ROR_ADD(s, 0x128);  // row_ror:8
  ROR_ADD(s, 0x124);  // row_ror:4
  ROR_ADD(s, 0x122);  // row_ror:2
  ROR_ADD(s, 0x121);  // row_ror:1
  return s;
}

__global__ __launch_bounds__(512) void gd_lagrange_kernel(
    const float* __restrict__ Yp,   // [128][16][1024]
    const float* __restrict__ Uk,   // [128][16][16]
    const float* __restrict__ Lm,   // [128][16][16]
    const float* __restrict__ Om0,  // [128][1024][16]
    const int* __restrict__ nitp,   // [1]
    float* __restrict__ out) {      // [128][1024][16]
  constexpr int S = 16, G = 1024;
  constexpr int YP_LD = 1028;  // pad keeps frag reads <=2-way banked, 16B-aligned rows

  const int wb  = blockIdx.x;
  const int tid = threadIdx.x;
  const int wv  = tid >> 6;         // wave 0..7
  const int q   = (tid >> 4) & 3;   // lane group
  const int m   = tid & 15;         // lane-in-row
  const int g0  = wv * 128;         // wave's g range

  __shared__ float ldsYp[S * YP_LD];        // 65.8 KB, staged Yp slice
  __shared__ float ldsRed[2][8][S * 17];    // 17.4 KB, double-buffered partials
  __shared__ float ldsUk[S * S];
  __shared__ float ldsLm[S * S];

  const float* ypg = Yp + (size_t)wb * (S * G);

  // ---- stage Yp slice (coalesced float4 -> padded LDS rows) ----
  #pragma unroll
  for (int k = 0; k < 8; ++k) {
    int vi  = k * 512 + tid;          // float4 index 0..4095
    f32x4 v = ((const f32x4*)ypg)[vi];
    int row = vi >> 8;                // (vi*4)/1024
    int col = (vi & 255) * 4;
    *(f32x4*)&ldsYp[row * YP_LD + col] = v;
  }
  if (tid < 256) {
    ldsUk[tid] = Uk[wb * 256 + tid];
    ldsLm[tid] = Lm[wb * 256 + tid];
  }
  __syncthreads();

  // ---- static Yp fragments (f16) ----
  // YpB[t] elem e = Yp[i=m][g0+16t+4q+e]      (B-frag of Yp^T for grad_lam^T)
  // YpA[t] elem e = Yp[s=4q+e][g0+16t+m]      (A-frag of YpT tile for grad_omega)
  f16x4 YpA[8], YpB[8];
  #pragma unroll
  for (int t = 0; t < 8; ++t) {
    int gt = g0 + 16 * t;
    f16x4 a, b;
    #pragma unroll
    for (int e = 0; e < 4; ++e) {
      b[e] = (_Float16)ldsYp[m * YP_LD + gt + 4 * q + e];
      a[e] = (_Float16)ldsYp[(4 * q + e) * YP_LD + gt + m];
    }
    YpA[t] = a; YpB[t] = b;
  }

  // ---- Omega master (f32), coalesced 64B-segment loads ----
  float Om[8][4];
  const float* omg = Om0 + (size_t)wb * (G * S);
  #pragma unroll
  for (int t = 0; t < 8; ++t)
    #pragma unroll
    for (int r = 0; r < 4; ++r)
      Om[t][r] = omg[(g0 + 16 * t + 4 * q + r) * S + m];

  // ---- target in lam's B-orientation: tgt[e] = (Uk@Lambda)[4q+e][m], f32 ----
  float tgt[4];
  #pragma unroll
  for (int e = 0; e < 4; ++e) {
    float s = 0.f;
    for (int k = 0; k < 16; ++k)
      s += ldsUk[(4 * q + e) * 16 + k] * ldsLm[k * 16 + m];
    tgt[e] = s;
  }

  float lam32[4] = {0.f, 0.f, 0.f, 0.f};  // lam[4q+e][m], f32 master
  const int niter = nitp[0];

  int buf = 0;
  for (int it = 0; it < niter; ++it) {
    // lam_old as f16 B-frag (grad_omega must use old lam)
    f16x4 lamB;
    #pragma unroll
    for (int e = 0; e < 4; ++e) lamB[e] = (_Float16)lam32[e];

    // Omega_old as f16 frags (grad_lam must use old Omega)
    f16x4 OmB[8];
    #pragma unroll
    for (int t = 0; t < 8; ++t) {
      f16x4 o;
      #pragma unroll
      for (int r = 0; r < 4; ++r) o[r] = (_Float16)Om[t][r];
      OmB[t] = o;
    }

    // ---- Phase B: partial grad_lam^T = Omega^T @ Yp^T over this wave's g ----
    f32x4 acc0 = {0.f, 0.f, 0.f, 0.f}, acc1 = {0.f, 0.f, 0.f, 0.f};
    #pragma unroll
    for (int t = 0; t < 8; t += 2) {
      acc0 = __builtin_amdgcn_mfma_f32_16x16x16f16(OmB[t],     YpB[t],     acc0, 0, 0, 0);
      acc1 = __builtin_amdgcn_mfma_f32_16x16x16f16(OmB[t + 1], YpB[t + 1], acc1, 0, 0, 0);
    }
    {
      // reg r holds (Yp@Om)[i=m][j=4q+r]; store as [i][j] (17-padded)
      float* rp = &ldsRed[buf][wv][m * 17 + 4 * q];
      rp[0] = acc0[0] + acc1[0];
      rp[1] = acc0[1] + acc1[1];
      rp[2] = acc0[2] + acc1[2];
      rp[3] = acc0[3] + acc1[3];
    }

    // ---- Phase C: grad_omega + Omega update (independent of the barrier) ----
    #pragma unroll
    for (int t = 0; t < 8; ++t) {
      f32x4 zero = {0.f, 0.f, 0.f, 0.f};
      f32x4 go = __builtin_amdgcn_mfma_f32_16x16x16f16(YpA[t], lamB, zero, 0, 0, 0);
      #pragma unroll
      for (int r = 0; r < 4; ++r) {
        float x    = Om[t][r];
        float n2   = rowsum16(x * x);                 // ||Omega_row||^2 over j
        float invn = __builtin_amdgcn_rsqf(n2);
        Om[t][r]   = x - MUv * (x * invn + go[r]);
      }
    }

    __syncthreads();  // all partials of buf written

    // ---- cross-wave reduce, transposed read -> lam[4q+e][m] update ----
    float gs[4] = {0.f, 0.f, 0.f, 0.f};
    #pragma unroll
    for (int w2 = 0; w2 < 8; ++w2) {
      const float* rr = ldsRed[buf][w2];
      #pragma unroll
      for (int e = 0; e < 4; ++e)
        gs[e] += rr[(4 * q + e) * 17 + m];
    }
    #pragma unroll
    for (int e = 0; e < 4; ++e)
      lam32[e] += ROv * (gs[e] - tgt[e]);

    buf ^= 1;  // double buffer => single barrier per iteration is race-free
  }

  // ---- store Omega ----
  float* og = out + (size_t)wb * (G * S);
  #pragma unroll
  for (int t = 0; t < 8; ++t)
    #pragma unroll
    for (int r = 0; r < 4; ++r)
      og[(g0 + 16 * t + 4 * q + r) * S + m] = Om[t][r];
}

extern "C" void kernel_launch(void* const* d_in, const int* in_sizes, int n_in,
                              void* d_out, int out_size, void* d_ws, size_t ws_size,
                              hipStream_t stream) {
  const float* Yp  = (const float*)d_in[0];
  const float* Uk  = (const float*)d_in[1];
  const float* Lm  = (const float*)d_in[2];
  const float* Om0 = (const float*)d_in[3];
  const int*   nit = (const int*)d_in[4];
  float* out = (float*)d_out;

  gd_lagrange_kernel<<<dim3(128), dim3(512), 0, stream>>>(Yp, Uk, Lm, Om0, nit, out);
}

// Round 3
// 38.092 us; speedup vs baseline: 1.1307x; 1.1307x over previous
//
#include <hip/hip_runtime.h>

// GD_lagrange_multi fused kernel for MI355X (gfx950).  Round 3 (compile fix of R2).
// Shapes fixed by setup_inputs(): W=4, B=32, S=16, G=1024, niter=20.
// One block per (w,b): 512 threads = 8 waves, wave owns 128 g-rows = 8 MFMA tiles.
//
// Unified lane layout (per 16x16 tile), lane l = 16*q + m (q=(l>>4)&3, m=l&15):
//   Omega master (f32): Om[t][r] = Omega[g = g0+16t+4q+r][j = m]        (C/D layout)
//   OmB[t] elem e      = Omega[g = g0+16t+4q+e][j = m]                  (B-frag, k=g)
//   YpB[t] elem e      = Yp[i = m][g = g0+16t+4q+e]                     (A-frag, k=g)
//   YpA[t] elem e      = Yp[s = 4q+e][g = g0+16t+m]                     (A-frag, k=s)
//   lamB    elem e     = lam[s = 4q+e][j = m]                           (B-frag, k=s)
// Phase B: mfma(YpB, OmB) = (Yp @ Omega) tile -> D[row=4q+r][col=m], which is
// EXACTLY the element lam32[r] needs — write pattern == read pattern, so the
// cross-wave reduce is pure b128 traffic with no transpose.
// Phase C: mfma(YpA, lamB) = (Yp^T @ lam) -> D[row(g)=4q+r][col(j)=m] == master.

typedef float    f32x4 __attribute__((ext_vector_type(4)));
typedef _Float16 f16x4 __attribute__((ext_vector_type(4)));
typedef __fp16   h16x2 __attribute__((ext_vector_type(2)));

#define MUv 1e-3f
#define ROv 1e-3f

// add value rotated within the 16-lane DPP row; 4 stages => all lanes hold row total
#define ROR_ADD(s, CTRL)                                                      \
  s += __int_as_float(__builtin_amdgcn_update_dpp(                            \
      0, __float_as_int(s), (CTRL), 0xF, 0xF, true))

__device__ __forceinline__ float rowsum16(float x) {
  float s = x;
  ROR_ADD(s, 0x128);  // row_ror:8
  ROR_ADD(s, 0x124);  // row_ror:4
  ROR_ADD(s, 0x122);  // row_ror:2
  ROR_ADD(s, 0x121);  // row_ror:1
  return s;
}

__device__ __forceinline__ f16x4 pack4(float a, float b, float c, float d) {
  h16x2 lo = __builtin_amdgcn_cvt_pkrtz(a, b);
  h16x2 hi = __builtin_amdgcn_cvt_pkrtz(c, d);
  union { struct { h16x2 lo, hi; } p; f16x4 v; } u;
  u.p.lo = lo; u.p.hi = hi;
  return u.v;
}

__global__ __launch_bounds__(512) void gd_lagrange_kernel(
    const float* __restrict__ Yp,   // [128][16][1024]
    const float* __restrict__ Uk,   // [128][16][16]
    const float* __restrict__ Lm,   // [128][16][16]
    const float* __restrict__ Om0,  // [128][1024][16]
    const int* __restrict__ nitp,   // [1]
    float* __restrict__ out) {      // [128][1024][16]
  constexpr int S = 16, G = 1024;
  constexpr int YP_LD = 1028;  // pad keeps frag reads <=2-way banked, 16B-aligned rows
  constexpr int RPAD  = 20;    // reduce-buffer row pitch (words); 16B-aligned starts

  const int wb  = blockIdx.x;
  const int tid = threadIdx.x;
  const int wv  = tid >> 6;         // wave 0..7
  const int q   = (tid >> 4) & 3;   // lane group
  const int m   = tid & 15;         // lane-in-row
  const int g0  = wv * 128;         // wave's g range

  __shared__ float ldsYp[S * YP_LD];          // 65.8 KB, staged Yp slice
  __shared__ float ldsRed[2][8][S * RPAD];    // 20.5 KB, double-buffered partials
  __shared__ float ldsUk[S * S];
  __shared__ float ldsLm[S * S];

  const float* ypg = Yp + (size_t)wb * (S * G);

  // ---- stage Yp slice (coalesced float4 -> padded LDS rows) ----
  #pragma unroll
  for (int k = 0; k < 8; ++k) {
    int vi  = k * 512 + tid;          // float4 index 0..4095
    f32x4 v = ((const f32x4*)ypg)[vi];
    int row = vi >> 8;                // (vi*4)/1024
    int col = (vi & 255) * 4;
    *(f32x4*)&ldsYp[row * YP_LD + col] = v;
  }
  if (tid < 256) {
    ldsUk[tid] = Uk[wb * 256 + tid];
    ldsLm[tid] = Lm[wb * 256 + tid];
  }
  __syncthreads();

  // ---- static Yp fragments (f16) ----
  f16x4 YpA[8], YpB[8];
  #pragma unroll
  for (int t = 0; t < 8; ++t) {
    int gt = g0 + 16 * t;
    YpB[t] = pack4(ldsYp[m * YP_LD + gt + 4 * q + 0],
                   ldsYp[m * YP_LD + gt + 4 * q + 1],
                   ldsYp[m * YP_LD + gt + 4 * q + 2],
                   ldsYp[m * YP_LD + gt + 4 * q + 3]);
    YpA[t] = pack4(ldsYp[(4 * q + 0) * YP_LD + gt + m],
                   ldsYp[(4 * q + 1) * YP_LD + gt + m],
                   ldsYp[(4 * q + 2) * YP_LD + gt + m],
                   ldsYp[(4 * q + 3) * YP_LD + gt + m]);
  }

  // ---- Omega master (f32), coalesced 64B-segment loads ----
  float Om[8][4];
  const float* omg = Om0 + (size_t)wb * (G * S);
  #pragma unroll
  for (int t = 0; t < 8; ++t)
    #pragma unroll
    for (int r = 0; r < 4; ++r)
      Om[t][r] = omg[(g0 + 16 * t + 4 * q + r) * S + m];

  // ---- target: tgt[e] = (Uk@Lambda)[4q+e][m], f32 ----
  float tgt[4];
  #pragma unroll
  for (int e = 0; e < 4; ++e) {
    float s = 0.f;
    for (int k = 0; k < 16; ++k)
      s += ldsUk[(4 * q + e) * 16 + k] * ldsLm[k * 16 + m];
    tgt[e] = s;
  }

  float lam32[4] = {0.f, 0.f, 0.f, 0.f};  // lam[4q+e][m], f32 master
  const int niter = nitp[0];
  const int rslot = m * RPAD + 4 * q;     // my b128 slot within a wave region

  int buf = 0;
  for (int it = 0; it < niter; ++it) {
    // f16 frags of OLD state (grad_lam uses old Omega; grad_omega uses old lam)
    f16x4 lamB = pack4(lam32[0], lam32[1], lam32[2], lam32[3]);
    f16x4 OmB[8];
    #pragma unroll
    for (int t = 0; t < 8; ++t)
      OmB[t] = pack4(Om[t][0], Om[t][1], Om[t][2], Om[t][3]);

    // ---- Phase B: partial (Yp @ Omega) over this wave's g (4 indep chains) ----
    f32x4 acc[4];
    #pragma unroll
    for (int c = 0; c < 4; ++c) acc[c] = (f32x4){0.f, 0.f, 0.f, 0.f};
    #pragma unroll
    for (int t = 0; t < 8; ++t)
      acc[t & 3] = __builtin_amdgcn_mfma_f32_16x16x16f16(YpB[t], OmB[t], acc[t & 3], 0, 0, 0);
    f32x4 g4 = (acc[0] + acc[1]) + (acc[2] + acc[3]);  // D[4q+r][m], r=0..3

    *(f32x4*)&ldsRed[buf][wv][rslot] = g4;   // one ds_write_b128

    __syncthreads();  // all partials of buf written

    // ---- issue cross-wave reduce loads (hide under Phase C) ----
    f32x4 part[8];
    #pragma unroll
    for (int w2 = 0; w2 < 8; ++w2)
      part[w2] = *(const f32x4*)&ldsRed[buf][w2][rslot];

    // ---- Phase C: grad_omega + Omega update (uses lamB = lam_old) ----
    #pragma unroll
    for (int t = 0; t < 8; ++t) {
      f32x4 zero = {0.f, 0.f, 0.f, 0.f};
      f32x4 go = __builtin_amdgcn_mfma_f32_16x16x16f16(YpA[t], lamB, zero, 0, 0, 0);
      #pragma unroll
      for (int r = 0; r < 4; ++r) {
        float x    = Om[t][r];
        float n2   = rowsum16(x * x);                 // ||Omega_row||^2 over j
        float invn = __builtin_amdgcn_rsqf(n2);
        float u    = fmaf(x, invn, go[r]);
        Om[t][r]   = fmaf(-MUv, u, x);
      }
    }

    // ---- consume reduce, update lam ----
    f32x4 gsum = ((part[0] + part[1]) + (part[2] + part[3])) +
                 ((part[4] + part[5]) + (part[6] + part[7]));
    #pragma unroll
    for (int e = 0; e < 4; ++e)
      lam32[e] += ROv * (gsum[e] - tgt[e]);

    buf ^= 1;  // double buffer => single barrier per iteration is race-free
  }

  // ---- store Omega ----
  float* og = out + (size_t)wb * (G * S);
  #pragma unroll
  for (int t = 0; t < 8; ++t)
    #pragma unroll
    for (int r = 0; r < 4; ++r)
      og[(g0 + 16 * t + 4 * q + r) * S + m] = Om[t][r];
}

extern "C" void kernel_launch(void* const* d_in, const int* in_sizes, int n_in,
                              void* d_out, int out_size, void* d_ws, size_t ws_size,
                              hipStream_t stream) {
  const float* Yp  = (const float*)d_in[0];
  const float* Uk  = (const float*)d_in[1];
  const float* Lm  = (const float*)d_in[2];
  const float* Om0 = (const float*)d_in[3];
  const int*   nit = (const int*)d_in[4];
  float* out = (float*)d_out;

  gd_lagrange_kernel<<<dim3(128), dim3(512), 0, stream>>>(Yp, Uk, Lm, Om0, nit, out);
}